// Round 2
// baseline (297.371 us; speedup 1.0000x reference)
//
#include <hip/hip_runtime.h>

#define INPUT_DIM 16
#define COLS 273                                   // 1 + 16 + 256
#define ROWS_PER_BLOCK 16
#define FLOATS_PER_BLOCK (ROWS_PER_BLOCK * COLS)   // 4368
#define VEC4_PER_BLOCK (FLOATS_PER_BLOCK / 4)      // 1092

// scales: 1/RRD = 1/d^0.25 = 0.5 ;  1/(sqrt(2)*sqrt(d)) = 1/(4*sqrt(2))
#define S1 0.5f
#define S2 0.17677669529663687f

__global__ __launch_bounds__(256)
void taylor_exp_kernel(const float* __restrict__ x, float* __restrict__ out)
{
    __shared__ float xs[ROWS_PER_BLOCK * INPUT_DIM];   // 1 KiB input tile
    __shared__ float os[FLOATS_PER_BLOCK];             // 17472 B output tile

    const int tid = threadIdx.x;
    const long long rowBase = (long long)blockIdx.x * ROWS_PER_BLOCK;

    // stage input tile: one coalesced 1 KiB load
    xs[tid] = x[rowBase * INPUT_DIM + tid];
    __syncthreads();

    // ---- compute phase: branch-free, division-free ----
    const int row = tid >> 4;          // 0..15
    const int l   = tid & 15;          // 0..15
    const int base = row * COLS;

    // own x value (identity-address LDS read, conflict-free)
    const float xl = xs[tid];

    // whole row of x into registers (broadcast reads, 4 addrs/wave)
    const float4* xsr = (const float4*)&xs[row * INPUT_DIM];
    const float4 r0 = xsr[0], r1 = xsr[1], r2 = xsr[2], r3 = xsr[3];

    // first-order term and the constant 1
    os[base + 1 + l] = xl * S1;
    if (l == 0) os[base] = 1.0f;

    // second-order: os[base + 17 + j*16 + l] = x[j]*x[l]*S2
    // consecutive lanes -> consecutive LDS addrs (conflict-free);
    // single addr reg + 16 immediate offsets (j*64 bytes)
    const float p = xl * S2;
    float* o2 = &os[base + 17 + l];
    o2[ 0 * 16] = r0.x * p;
    o2[ 1 * 16] = r0.y * p;
    o2[ 2 * 16] = r0.z * p;
    o2[ 3 * 16] = r0.w * p;
    o2[ 4 * 16] = r1.x * p;
    o2[ 5 * 16] = r1.y * p;
    o2[ 6 * 16] = r1.z * p;
    o2[ 7 * 16] = r1.w * p;
    o2[ 8 * 16] = r2.x * p;
    o2[ 9 * 16] = r2.y * p;
    o2[10 * 16] = r2.z * p;
    o2[11 * 16] = r2.w * p;
    o2[12 * 16] = r3.x * p;
    o2[13 * 16] = r3.y * p;
    o2[14 * 16] = r3.z * p;
    o2[15 * 16] = r3.w * p;

    __syncthreads();

    // ---- copy phase: pure LDS -> global stream, zero arithmetic ----
    float4* __restrict__ out4 = (float4*)(out + (long long)blockIdx.x * FLOATS_PER_BLOCK);
    const float4* os4 = (const float4*)os;

    #pragma unroll
    for (int it = 0; it < 5; ++it) {
        const int v = tid + it * 256;        // 1092 = 4*256 + 68
        if (v < VEC4_PER_BLOCK) {
            out4[v] = os4[v];
        }
    }
}

extern "C" void kernel_launch(void* const* d_in, const int* in_sizes, int n_in,
                              void* d_out, int out_size, void* d_ws, size_t ws_size,
                              hipStream_t stream)
{
    const float* x = (const float*)d_in[0];
    float* out = (float*)d_out;

    const int nrows  = in_sizes[0] / INPUT_DIM;        // 262144
    const int blocks = nrows / ROWS_PER_BLOCK;         // 16384

    taylor_exp_kernel<<<blocks, 256, 0, stream>>>(x, out);
}

// Round 5
// 293.049 us; speedup vs baseline: 1.0147x; 1.0147x over previous
//
#include <hip/hip_runtime.h>

#define INPUT_DIM 16
#define COLS 273                                   // 1 + 16 + 256
#define ROWS_PER_BLOCK 16
#define FLOATS_PER_BLOCK (ROWS_PER_BLOCK * COLS)   // 4368
#define VEC4_PER_BLOCK (FLOATS_PER_BLOCK / 4)      // 1092

// scales: 1/RRD = 1/d^0.25 = 0.5 ;  1/(sqrt(2)*sqrt(d)) = 1/(4*sqrt(2))
#define S1 0.5f
#define S2 0.17677669529663687f

typedef float f4 __attribute__((ext_vector_type(4)));

__global__ __launch_bounds__(256)
void taylor_exp_kernel(const float* __restrict__ x, float* __restrict__ out)
{
    __shared__ float xs[ROWS_PER_BLOCK * INPUT_DIM];   // 1 KiB input tile
    __shared__ float os[FLOATS_PER_BLOCK];             // 17472 B output tile

    const int tid = threadIdx.x;
    const long long rowBase = (long long)blockIdx.x * ROWS_PER_BLOCK;

    // stage input tile: one coalesced 1 KiB load
    xs[tid] = x[rowBase * INPUT_DIM + tid];
    __syncthreads();

    // ---- compute phase: branch-free, division-free ----
    const int row = tid >> 4;          // 0..15
    const int l   = tid & 15;          // 0..15
    const int base = row * COLS;

    const float xl = xs[tid];          // own x value

    // whole row of x into registers (broadcast reads)
    const f4* xsr = (const f4*)&xs[row * INPUT_DIM];
    const f4 r0 = xsr[0], r1 = xsr[1], r2 = xsr[2], r3 = xsr[3];

    // first-order term and the constant 1
    os[base + 1 + l] = xl * S1;
    if (l == 0) os[base] = 1.0f;

    // second-order: os[base + 17 + j*16 + l] = (x[j]*x[l])*S2
    // (product-then-scale order matches reference rounding, absmax==0 in R1)
    float* o2 = &os[base + 17 + l];
    o2[ 0 * 16] = (r0[0] * xl) * S2;
    o2[ 1 * 16] = (r0[1] * xl) * S2;
    o2[ 2 * 16] = (r0[2] * xl) * S2;
    o2[ 3 * 16] = (r0[3] * xl) * S2;
    o2[ 4 * 16] = (r1[0] * xl) * S2;
    o2[ 5 * 16] = (r1[1] * xl) * S2;
    o2[ 6 * 16] = (r1[2] * xl) * S2;
    o2[ 7 * 16] = (r1[3] * xl) * S2;
    o2[ 8 * 16] = (r2[0] * xl) * S2;
    o2[ 9 * 16] = (r2[1] * xl) * S2;
    o2[10 * 16] = (r2[2] * xl) * S2;
    o2[11 * 16] = (r2[3] * xl) * S2;
    o2[12 * 16] = (r3[0] * xl) * S2;
    o2[13 * 16] = (r3[1] * xl) * S2;
    o2[14 * 16] = (r3[2] * xl) * S2;
    o2[15 * 16] = (r3[3] * xl) * S2;

    __syncthreads();

    // ---- copy phase: LDS -> global, NON-TEMPORAL (bypass L2/L3 allocate) ----
    f4* __restrict__ out4 = (f4*)(out + (long long)blockIdx.x * FLOATS_PER_BLOCK);
    const f4* os4 = (const f4*)os;

    #pragma unroll
    for (int it = 0; it < 5; ++it) {
        const int v = tid + it * 256;        // 1092 = 4*256 + 68
        if (v < VEC4_PER_BLOCK) {
            __builtin_nontemporal_store(os4[v], &out4[v]);
        }
    }
}

extern "C" void kernel_launch(void* const* d_in, const int* in_sizes, int n_in,
                              void* d_out, int out_size, void* d_ws, size_t ws_size,
                              hipStream_t stream)
{
    const float* x = (const float*)d_in[0];
    float* out = (float*)d_out;

    const int nrows  = in_sizes[0] / INPUT_DIM;        // 262144
    const int blocks = nrows / ROWS_PER_BLOCK;         // 16384

    taylor_exp_kernel<<<blocks, 256, 0, stream>>>(x, out);
}